// Round 17
// baseline (5982.101 us; speedup 1.0000x reference)
//
#include <hip/hip_runtime.h>
#include <math.h>

#define NI  2
#define BB  32
#define DD  512
#define HWX 324
#define LL  648
#define MM  648
#define KX  128

#define TEMPF  30.0f
#define NEPSF  1e-5f
#define L2EPSF 1e-12f
#define DHWF   165888.0f
#define NSDF   0.011048543456039806f

typedef float f8v __attribute__((ext_vector_type(8)));

// ---------- staging: x = flat(tgt) + 0.001*flat(pe)  (layer-0 addpe fused) ---
__global__ void k_flat(const float* __restrict__ src, const float* __restrict__ pe,
                       float* __restrict__ x) {
  size_t idx = (size_t)blockIdx.x * 256 + threadIdx.x;
  int r = (int)(idx >> 9), d = (int)(idx & 511);
  int l = r >> 5, b = r & 31;
  int i = l / HWX, s = l % HWX;
  size_t sidx = ((size_t)(i * BB + b) * DD + d) * HWX + s;
  float v = src[sidx];
  float t = __fmul_rn(pe[sidx], 0.001f);
  x[idx] = __fadd_rn(v, t);
}

__global__ void k_pos(const float* __restrict__ pos, float* __restrict__ ps) {
  int idx = blockIdx.x * 256 + threadIdx.x;  // 20736
  int l = idx >> 5, b = idx & 31;
  int j = l / HWX, s = l % HWX;
  ps[idx] = pos[((size_t)(j * BB + b)) * HWX + s];
}

__global__ void k_memp(const float* __restrict__ mem, const float* __restrict__ ps,
                       float* __restrict__ memp) {
  size_t idx = (size_t)blockIdx.x * 256 + threadIdx.x;
  memp[idx] = __fmul_rn(mem[idx], ps[idx >> 9]);
}

__global__ void k_wt(const float* __restrict__ W, float* __restrict__ Wt) {
  int idx = blockIdx.x * 256 + threadIdx.x;  // 65536: dst [d][k]
  int k = idx & 127, d = idx >> 7;
  Wt[idx] = W[(size_t)k * DD + d];
}

// ---------- projection + bias + l2norm: 64-row tiles, 256 thr (chains = r7) --
__global__ __launch_bounds__(256) void k_projt(const float* __restrict__ A,
                                               const float* __restrict__ Wt,
                                               const float* __restrict__ bias,
                                               float* __restrict__ outp) {
  int r0 = blockIdx.x * 64;   // grid 324, 324*64 = 20736 exact
  int tid = threadIdx.x, tx = tid & 15, ty = tid >> 4;  // ty 0..15
  __shared__ float As[64][36];
  __shared__ float Ws[32][132];
  __shared__ float bsh[128];
  __shared__ float sqb[16][129];
  __shared__ float prb[16][8];
  __shared__ float nshs[16];
  if (tid < 128) bsh[tid] = bias[tid];
  float acc[4][8] = {};
  for (int d0 = 0; d0 < 512; d0 += 32) {
#pragma unroll
    for (int n = 0; n < 2; n++) {
      int fi = tid + 256 * n;  // 512 float4: As 64x8
      int rr = fi >> 3, dq = (fi & 7) * 4;
      *(float4*)&As[rr][dq] = *(const float4*)(A + (size_t)(r0 + rr) * 512 + d0 + dq);
    }
#pragma unroll
    for (int n = 0; n < 4; n++) {
      int fi = tid + 256 * n;  // 1024 float4: Ws 32x32
      int dd = fi >> 5, kq = (fi & 31) * 4;
      *(float4*)&Ws[dd][kq] = *(const float4*)(Wt + (size_t)(d0 + dd) * 128 + kq);
    }
    __syncthreads();
#pragma unroll 8
    for (int dd = 0; dd < 32; dd++) {
      float a[4], w[8];
#pragma unroll
      for (int i = 0; i < 4; i++) a[i] = As[ty + 16 * i][dd];
#pragma unroll
      for (int j = 0; j < 8; j++) w[j] = Ws[dd][tx + 16 * j];
#pragma unroll
      for (int i = 0; i < 4; i++)
#pragma unroll
        for (int j = 0; j < 8; j++) acc[i][j] = fmaf(a[i], w[j], acc[i][j]);
    }
    __syncthreads();
  }
  for (int i = 0; i < 4; i++) {
    float val[8];
#pragma unroll
    for (int j = 0; j < 8; j++) {
      val[j] = __fadd_rn(acc[i][j], bsh[tx + 16 * j]);
      sqb[ty][tx + 16 * j] = __fmul_rn(val[j], val[j]);
    }
    __syncthreads();
    if (tid < 128) {
      int row = tid >> 3, jj = tid & 7;
      float rr = sqb[row][jj];
      for (int blk = 1; blk < 16; blk++) rr += sqb[row][blk * 8 + jj];
      prb[row][jj] = rr;
    }
    __syncthreads();
    if (tid < 16) {
      float* p = prb[tid];
      float ss = ((p[0] + p[1]) + (p[2] + p[3])) + ((p[4] + p[5]) + (p[6] + p[7]));
      nshs[tid] = fmaxf(__fsqrt_rn(ss), L2EPSF);
    }
    __syncthreads();
    float nsh = nshs[ty];
    int r = r0 + ty + 16 * i;
#pragma unroll
    for (int j = 0; j < 8; j++)
      outp[(size_t)r * 128 + tx + 16 * j] = __fdiv_rn(val[j], nsh);
    __syncthreads();
  }
}

// ---------- scores 96x96 tiles: sc[(b*648+q)*648+s] = 30 * k-chain fmaf ------
__global__ __launch_bounds__(256) void k_scoret(const float* __restrict__ wqp,
                                                const float* __restrict__ wkp,
                                                float* __restrict__ sc) {
  int q0 = blockIdx.x * 96, s0 = blockIdx.y * 96, b = blockIdx.z;
  int tid = threadIdx.x, tx = tid & 15, ty = tid >> 4;
  __shared__ float QsT[32][97];   // kk-major (transposed)
  __shared__ float Ks[96][36];    // row-major
  float acc[6][6] = {};
  const float4 f40 = make_float4(0.f, 0.f, 0.f, 0.f);
  for (int k0 = 0; k0 < 128; k0 += 32) {
#pragma unroll
    for (int n = 0; n < 3; n++) {
      int fi = tid + 256 * n;  // 0..767
      int rr = fi >> 3, kq = (fi & 7) * 4;
      int q = q0 + rr;
      float4 v = (q < LL) ? *(const float4*)(wqp + ((size_t)q * 32 + b) * 128 + k0 + kq) : f40;
      QsT[kq + 0][rr] = v.x; QsT[kq + 1][rr] = v.y;
      QsT[kq + 2][rr] = v.z; QsT[kq + 3][rr] = v.w;
      int s = s0 + rr;
      float4 w = (s < MM) ? *(const float4*)(wkp + ((size_t)s * 32 + b) * 128 + k0 + kq) : f40;
      *(float4*)&Ks[rr][kq] = w;
    }
    __syncthreads();
#pragma unroll 8
    for (int kk = 0; kk < 32; kk++) {
      float a[6], w[6];
#pragma unroll
      for (int i = 0; i < 6; i++) a[i] = QsT[kk][ty + 16 * i];
#pragma unroll
      for (int j = 0; j < 6; j++) w[j] = Ks[tx + 16 * j][kk];
#pragma unroll
      for (int i = 0; i < 6; i++)
#pragma unroll
        for (int j = 0; j < 6; j++) acc[i][j] = fmaf(a[i], w[j], acc[i][j]);
    }
    __syncthreads();
  }
#pragma unroll
  for (int i = 0; i < 6; i++) {
    int q = q0 + ty + 16 * i;
    if (q >= LL) continue;
    float* orow = sc + ((size_t)b * LL + q) * MM;
#pragma unroll
    for (int j = 0; j < 6; j++) {
      int s = s0 + tx + 16 * j;
      if (s < MM) orow[s] = __fmul_rn(acc[i][j], TEMPF);
    }
  }
}

// ---------- softmax (+ optional fused mask chain, verbatim k_mask order) -----
template <int DO_MASK>
__global__ __launch_bounds__(256) void k_sm2(float* __restrict__ sc,
                                             const float* __restrict__ ps,
                                             float* __restrict__ msk) {
  int row = blockIdx.x;
  float* p = sc + (size_t)row * MM;
  int t = threadIdx.x;
  __shared__ float red[256];
  __shared__ float es[MM];
  __shared__ float psl[MM];
  __shared__ float prc[64];
  __shared__ float ssum;
  int b = row / LL, q = row - b * LL;
  if (DO_MASK) {
    for (int s = t; s < MM; s += 256) psl[s] = ps[s * 32 + b];
  }
  float v0 = p[t], v1 = p[t + 256];
  bool h2 = t < (MM - 512);
  float v2 = h2 ? p[t + 512] : -3.0e38f;
  red[t] = fmaxf(fmaxf(v0, v1), v2);
  __syncthreads();
  for (int off = 128; off; off >>= 1) {
    if (t < off) red[t] = fmaxf(red[t], red[t + off]);
    __syncthreads();
  }
  float mx = red[0];
  float e0 = (float)exp((double)__fsub_rn(v0, mx));
  float e1 = (float)exp((double)__fsub_rn(v1, mx));
  float e2 = h2 ? (float)exp((double)__fsub_rn(v2, mx)) : 0.0f;
  es[t] = e0; es[t + 256] = e1;
  if (h2) es[t + 512] = e2;
  __syncthreads();
  if (t < 64) {
    int c = t >> 3, jj = t & 7;
    int base = c * 80, n = (c == 7) ? 88 : 80;
    float r = es[base + jj];
    for (int i = 8; i < n; i += 8) r += es[base + i + jj];
    prc[t] = r;
  }
  __syncthreads();
  if (t == 0) {
    float pc[8];
#pragma unroll
    for (int c = 0; c < 8; c++) {
      float* pp = prc + c * 8;
      pc[c] = ((pp[0] + pp[1]) + (pp[2] + pp[3])) + ((pp[4] + pp[5]) + (pp[6] + pp[7]));
    }
    float lsum = (pc[0] + pc[1]) + (pc[2] + pc[3]);
    float rsum = (pc[4] + pc[5]) + (pc[6] + pc[7]);
    ssum = lsum + rsum;
  }
  __syncthreads();
  float s = ssum;
  float d0 = __fdiv_rn(e0, s), d1 = __fdiv_rn(e1, s);
  p[t] = d0; p[t + 256] = d1;
  float d2 = 0.f;
  if (h2) { d2 = __fdiv_rn(e2, s); p[t + 512] = d2; }
  if (DO_MASK) {
    es[t] = d0; es[t + 256] = d1;
    if (h2) es[t + 512] = d2;
    __syncthreads();
    if (t == 0) {  // verbatim k_mask chain: s-ascending fmaf over divided values
      float a = 0.0f;
      for (int ss2 = 0; ss2 < MM; ss2++) a = fmaf(es[ss2], psl[ss2], a);
      msk[q * 32 + b] = a;
    }
  }
}

// ---------- apply: Q=12, 256 threads, s_load_dwordx8 aff, float2 V -----------
// XCD-chunked swizzle: 1728 = 8 xcd * (4 b * 54 q-blocks)
// out[(q*32+b)][d] = s-chain fmaf (s ascending)
__global__ __launch_bounds__(256) void k_applyg(const float* __restrict__ aff,
                                                const float* __restrict__ V,
                                                float* __restrict__ outp) {
  int dd = blockIdx.x;             // 0..1727
  int xcd = dd & 7, j = dd >> 3;   // each XCD owns 4 batches
  int b = xcd * 4 + j / 54;
  int q0 = (j % 54) * 12;
  int tid = threadIdx.x;
  const float* abase = aff + ((size_t)b * LL + q0) * MM;
  const float* vbase = V + (size_t)b * 512 + tid * 2;
  float acc0[12] = {};
  float acc1[12] = {};
  for (int s8 = 0; s8 < 81; s8++) {
    float2 v0 = *(const float2*)(vbase + (size_t)(8 * s8 + 0) * 16384);
    float2 v1 = *(const float2*)(vbase + (size_t)(8 * s8 + 1) * 16384);
    float2 v2 = *(const float2*)(vbase + (size_t)(8 * s8 + 2) * 16384);
    float2 v3 = *(const float2*)(vbase + (size_t)(8 * s8 + 3) * 16384);
    float2 v4 = *(const float2*)(vbase + (size_t)(8 * s8 + 4) * 16384);
    float2 v5 = *(const float2*)(vbase + (size_t)(8 * s8 + 5) * 16384);
    float2 v6 = *(const float2*)(vbase + (size_t)(8 * s8 + 6) * 16384);
    float2 v7 = *(const float2*)(vbase + (size_t)(8 * s8 + 7) * 16384);
#pragma unroll
    for (int qq = 0; qq < 12; qq++) {
      f8v a8 = *(const f8v*)(abase + qq * MM + s8 * 8);  // wave-uniform 32B
      acc0[qq] = fmaf(a8[0], v0.x, acc0[qq]); acc1[qq] = fmaf(a8[0], v0.y, acc1[qq]);
      acc0[qq] = fmaf(a8[1], v1.x, acc0[qq]); acc1[qq] = fmaf(a8[1], v1.y, acc1[qq]);
      acc0[qq] = fmaf(a8[2], v2.x, acc0[qq]); acc1[qq] = fmaf(a8[2], v2.y, acc1[qq]);
      acc0[qq] = fmaf(a8[3], v3.x, acc0[qq]); acc1[qq] = fmaf(a8[3], v3.y, acc1[qq]);
      acc0[qq] = fmaf(a8[4], v4.x, acc0[qq]); acc1[qq] = fmaf(a8[4], v4.y, acc1[qq]);
      acc0[qq] = fmaf(a8[5], v5.x, acc0[qq]); acc1[qq] = fmaf(a8[5], v5.y, acc1[qq]);
      acc0[qq] = fmaf(a8[6], v6.x, acc0[qq]); acc1[qq] = fmaf(a8[6], v6.y, acc1[qq]);
      acc0[qq] = fmaf(a8[7], v7.x, acc0[qq]); acc1[qq] = fmaf(a8[7], v7.y, acc1[qq]);
    }
  }
#pragma unroll
  for (int qq = 0; qq < 12; qq++) {
    float2 r = make_float2(acc0[qq], acc1[qq]);
    *(float2*)(outp + ((size_t)(q0 + qq) * 32 + b) * 512 + tid * 2) = r;
  }
}

// ---------- instance-norm stage A (verbatim) ---------------------------------
template <int MODE>
__global__ __launch_bounds__(128) void k_na(const float* __restrict__ x,
                                            const float* __restrict__ ao,
                                            const float* __restrict__ msk,
                                            const float* __restrict__ scu,
                                            const float* __restrict__ scv,
                                            float* __restrict__ tU,
                                            float* __restrict__ tV) {
  int s = blockIdx.x;
  int g = blockIdx.y;
  int i = g >> 5, b = g & 31;
  int l = i * HWX + s;
  size_t base = ((size_t)l * BB + b) * DD;
  int t = threadIdx.x;
  __shared__ float squ[DD];
  __shared__ float sqv[DD];
  __shared__ float pru[32];
  __shared__ float prv[32];
  float mk = 0.f, su = 0.f, sv = 0.f;
  if (MODE >= 2) mk = msk[l * BB + b];
  if (MODE == 3) { su = scu[g]; sv = scv[g]; }
  for (int d = t; d < DD; d += 128) {
    float xx = x[base + d];
    if (MODE == 1) {
      float y = __fadd_rn(xx, ao[base + d]);
      squ[d] = __fmul_rn(y, y);
    } else if (MODE == 2) {
      float u = __fmul_rn(xx, mk);
      float v = __fadd_rn(xx, ao[base + d]);
      squ[d] = __fmul_rn(u, u);
      sqv[d] = __fmul_rn(v, v);
    } else {
      float u = __fmul_rn(xx, mk);
      float v = __fadd_rn(xx, ao[base + d]);
      float t2 = __fmul_rn(u, su);
      float t4 = __fmul_rn(v, sv);
      float w = __fadd_rn(t2, t4);
      squ[d] = __fmul_rn(w, w);
    }
  }
  __syncthreads();
  if (t < 32) {
    int c = t >> 3, jj = t & 7, b0 = c * 128;
    float r = squ[b0 + jj];
    for (int blk = 1; blk < 16; blk++) r += squ[b0 + blk * 8 + jj];
    pru[t] = r;
    if (MODE == 2) {
      float r2 = sqv[b0 + jj];
      for (int blk = 1; blk < 16; blk++) r2 += sqv[b0 + blk * 8 + jj];
      prv[t] = r2;
    }
  }
  __syncthreads();
  if (t == 0) {
    float cc[4];
    for (int c = 0; c < 4; c++)
      cc[c] = ((pru[c * 8] + pru[c * 8 + 1]) + (pru[c * 8 + 2] + pru[c * 8 + 3])) +
              ((pru[c * 8 + 4] + pru[c * 8 + 5]) + (pru[c * 8 + 6] + pru[c * 8 + 7]));
    tU[g * HWX + s] = (cc[0] + cc[1]) + (cc[2] + cc[3]);
    if (MODE == 2) {
      for (int c = 0; c < 4; c++)
        cc[c] = ((prv[c * 8] + prv[c * 8 + 1]) + (prv[c * 8 + 2] + prv[c * 8 + 3])) +
                ((prv[c * 8 + 4] + prv[c * 8 + 5]) + (prv[c * 8 + 6] + prv[c * 8 + 7]));
      tV[g * HWX + s] = (cc[0] + cc[1]) + (cc[2] + cc[3]);
    }
  }
}

__global__ void k_fin1(const float* __restrict__ tU, float* __restrict__ scl) {
  int g = threadIdx.x;
  float ss = 0.0f;
  for (int s4 = 0; s4 < 81; s4++) {
    float4 t = *(const float4*)(tU + g * HWX + s4 * 4);
    ss += t.x; ss += t.y; ss += t.z; ss += t.w;
  }
  scl[g] = __fmul_rn(NSDF, __fsqrt_rn(__fdiv_rn(DHWF, __fadd_rn(ss, NEPSF))));
}

__global__ void k_fin2(const float* __restrict__ tU, const float* __restrict__ tV,
                       float* __restrict__ scu, float* __restrict__ scv) {
  int g = threadIdx.x;
  float su = 0.0f, sv = 0.0f;
  for (int s4 = 0; s4 < 81; s4++) {
    float4 t = *(const float4*)(tU + g * HWX + s4 * 4);
    float4 t2 = *(const float4*)(tV + g * HWX + s4 * 4);
    su += t.x; su += t.y; su += t.z; su += t.w;
    sv += t2.x; sv += t2.y; sv += t2.z; sv += t2.w;
  }
  scu[g] = __fmul_rn(NSDF, __fsqrt_rn(__fdiv_rn(DHWF, __fadd_rn(su, NEPSF))));
  scv[g] = __fmul_rn(NSDF, __fsqrt_rn(__fdiv_rn(DHWF, __fadd_rn(sv, NEPSF))));
}

__global__ void k_a1(float* __restrict__ x, const float* __restrict__ ao,
                     const float* __restrict__ scl) {
  size_t idx = (size_t)blockIdx.x * 256 + threadIdx.x;
  int r = (int)(idx >> 9);
  int l = r >> 5, b = r & 31;
  int g = (l / HWX) * BB + b;
  x[idx] = __fmul_rn(__fadd_rn(x[idx], ao[idx]), scl[g]);
}

// ---------- a2 (+ optional fused next-layer addpe, bit-identical chain) ------
template <int ADDPE>
__global__ void k_a2(float* __restrict__ x, const float* __restrict__ ao,
                     const float* __restrict__ msk, const float* __restrict__ scu,
                     const float* __restrict__ scv, const float* __restrict__ scw,
                     const float* __restrict__ pe) {
  size_t idx = (size_t)blockIdx.x * 256 + threadIdx.x;
  int r = (int)(idx >> 9);
  int l = r >> 5, b = r & 31;
  int g = (l / HWX) * BB + b;
  float mk = msk[l * BB + b];
  float xx = x[idx];
  float u = __fmul_rn(xx, mk);
  float v = __fadd_rn(xx, ao[idx]);
  float t2 = __fmul_rn(u, scu[g]);
  float t4 = __fmul_rn(v, scv[g]);
  float w = __fadd_rn(t2, t4);
  float res = __fmul_rn(w, scw[g]);
  if (ADDPE) {
    int d = (int)(idx & 511);
    int i = l / HWX, s = l % HWX;
    float t = __fmul_rn(pe[((size_t)(i * BB + b) * DD + d) * HWX + s], 0.001f);
    res = __fadd_rn(res, t);
  }
  x[idx] = res;
}

// ---------- outputs ----------------------------------------------------------
__global__ void k_o0(const float* __restrict__ x, float* __restrict__ out) {
  size_t idx = (size_t)blockIdx.x * 256 + threadIdx.x;
  out[idx] = x[idx];
}

__global__ void k_o1(const float* __restrict__ x, float* __restrict__ out1) {
  size_t idx = (size_t)blockIdx.x * 256 + threadIdx.x;
  int s = (int)(idx % HWX);
  int d = (int)((idx / HWX) & 511);
  int ib = (int)(idx / ((size_t)HWX * DD));
  int i = ib >> 5, b = ib & 31;
  int l = i * HWX + s;
  out1[idx] = x[((size_t)l * BB + b) * DD + d];
}

// ---------------------------------------------------------------------------
extern "C" void kernel_launch(void* const* d_in, const int* in_sizes, int n_in,
                              void* d_out, int out_size, void* d_ws, size_t ws_size,
                              hipStream_t stream) {
  const float* tgt = (const float*)d_in[0];
  const float* pe  = (const float*)d_in[1];
  const float* mem = (const float*)d_in[2];
  const float* pos = (const float*)d_in[3];
  const float* Wks = (const float*)d_in[4];
  const float* bks = (const float*)d_in[5];
  const float* Wkc = (const float*)d_in[6];
  const float* bkc = (const float*)d_in[7];
  float* out = (float*)d_out;

  // 50,810,112 floats = 203,240,448 bytes
  if (ws_size < (size_t)203240448) return;
  float* f = (float*)d_ws;
  float* x    = f;                  // 10,616,832  [l,b,d]
  float* ao   = f + 10616832;       // 10,616,832
  float* memp = f + 21233664;       // 10,616,832
  float* wq   = f + 31850496;       //  2,654,208  [l,b,k]
  float* wkm  = f + 34504704;       //  2,654,208
  float* sc   = f + 37158912;       // 13,436,928  [b,q,s]
  float* msk  = f + 50595840;       //     20,736  [q,b]
  float* ps   = f + 50616576;       //     20,736  [l,b]
  float* tU   = f + 50637312;       //     20,736
  float* tV   = f + 50658048;       //     20,736
  float* scl  = f + 50678784;       //        256
  float* scu  = scl + 64;
  float* scv  = scl + 128;
  float* scw  = scl + 192;
  float* Wst  = f + 50679040;       //     65,536  [d,k]
  float* Wct  = f + 50744576;       //     65,536

  k_wt<<<256, 256, 0, stream>>>(Wks, Wst);
  k_wt<<<256, 256, 0, stream>>>(Wkc, Wct);
  k_flat<<<41472, 256, 0, stream>>>(tgt, pe, x);   // layer-0 addpe fused
  k_pos<<<81, 256, 0, stream>>>(pos, ps);
  k_memp<<<41472, 256, 0, stream>>>(mem, ps, memp);
  // loop-invariant cross keys from memory
  k_projt<<<324, 256, 0, stream>>>(mem, Wct, bkc, wkm);

  dim3 scg(7, 7, 32);
  dim3 nag(324, 64);
  for (int l = 0; l < 6; l++) {
    // --- self-attention (q=k=v=x) --- (x already has pe added)
    k_projt<<<324, 256, 0, stream>>>(x, Wst, bks, wq);
    k_scoret<<<scg, 256, 0, stream>>>(wq, wq, sc);
    k_sm2<0><<<20736, 256, 0, stream>>>(sc, nullptr, nullptr);
    k_applyg<<<1728, 256, 0, stream>>>(sc, x, ao);
    k_na<1><<<nag, 128, 0, stream>>>(x, ao, nullptr, nullptr, nullptr, tU, nullptr);
    k_fin1<<<1, 64, 0, stream>>>(tU, scl);
    k_a1<<<41472, 256, 0, stream>>>(x, ao, scl);
    // --- cross-attention: shared softmax; mask fused into softmax ---
    k_projt<<<324, 256, 0, stream>>>(x, Wct, bkc, wq);
    k_scoret<<<scg, 256, 0, stream>>>(wq, wkm, sc);
    k_sm2<1><<<20736, 256, 0, stream>>>(sc, ps, msk);
    k_applyg<<<1728, 256, 0, stream>>>(sc, memp, ao);
    k_na<2><<<nag, 128, 0, stream>>>(x, ao, msk, nullptr, nullptr, tU, tV);
    k_fin2<<<1, 64, 0, stream>>>(tU, tV, scu, scv);
    k_na<3><<<nag, 128, 0, stream>>>(x, ao, msk, scu, scv, tU, nullptr);
    k_fin1<<<1, 64, 0, stream>>>(tU, scw);
    if (l < 5)
      k_a2<1><<<41472, 256, 0, stream>>>(x, ao, msk, scu, scv, scw, pe);
    else
      k_a2<0><<<41472, 256, 0, stream>>>(x, ao, msk, scu, scv, scw, nullptr);
  }

  k_o0<<<41472, 256, 0, stream>>>(x, out);
  k_o1<<<41472, 256, 0, stream>>>(x, out + (size_t)LL * BB * DD);
}

// Round 18
// 5570.027 us; speedup vs baseline: 1.0740x; 1.0740x over previous
//
#include <hip/hip_runtime.h>
#include <math.h>

#define NI  2
#define BB  32
#define DD  512
#define HWX 324
#define LL  648
#define MM  648
#define KX  128

#define TEMPF  30.0f
#define NEPSF  1e-5f
#define L2EPSF 1e-12f
#define DHWF   165888.0f
#define NSDF   0.011048543456039806f

typedef float f8v __attribute__((ext_vector_type(8)));

// ---------- staging: x = flat(tgt) + 0.001*flat(pe)  (layer-0 addpe fused) ---
__global__ void k_flat(const float* __restrict__ src, const float* __restrict__ pe,
                       float* __restrict__ x) {
  size_t idx = (size_t)blockIdx.x * 256 + threadIdx.x;
  int r = (int)(idx >> 9), d = (int)(idx & 511);
  int l = r >> 5, b = r & 31;
  int i = l / HWX, s = l % HWX;
  size_t sidx = ((size_t)(i * BB + b) * DD + d) * HWX + s;
  float v = src[sidx];
  float t = __fmul_rn(pe[sidx], 0.001f);
  x[idx] = __fadd_rn(v, t);
}

__global__ void k_pos(const float* __restrict__ pos, float* __restrict__ ps) {
  int idx = blockIdx.x * 256 + threadIdx.x;  // 20736
  int l = idx >> 5, b = idx & 31;
  int j = l / HWX, s = l % HWX;
  ps[idx] = pos[((size_t)(j * BB + b)) * HWX + s];
}

__global__ void k_memp(const float* __restrict__ mem, const float* __restrict__ ps,
                       float* __restrict__ memp) {
  size_t idx = (size_t)blockIdx.x * 256 + threadIdx.x;
  memp[idx] = __fmul_rn(mem[idx], ps[idx >> 9]);
}

__global__ void k_wt(const float* __restrict__ W, float* __restrict__ Wt) {
  int idx = blockIdx.x * 256 + threadIdx.x;  // 65536: dst [d][k]
  int k = idx & 127, d = idx >> 7;
  Wt[idx] = W[(size_t)k * DD + d];
}

// ---------- projection + bias + l2norm: 64-row tiles, 256 thr (chains = r7) --
__global__ __launch_bounds__(256) void k_projt(const float* __restrict__ A,
                                               const float* __restrict__ Wt,
                                               const float* __restrict__ bias,
                                               float* __restrict__ outp) {
  int r0 = blockIdx.x * 64;   // grid 324
  int tid = threadIdx.x, tx = tid & 15, ty = tid >> 4;  // ty 0..15
  __shared__ float As[64][36];
  __shared__ float Ws[32][132];
  __shared__ float bsh[128];
  __shared__ float sqb[16][129];
  __shared__ float prb[16][8];
  __shared__ float nshs[16];
  if (tid < 128) bsh[tid] = bias[tid];
  float acc[4][8] = {};
  for (int d0 = 0; d0 < 512; d0 += 32) {
#pragma unroll
    for (int n = 0; n < 2; n++) {
      int fi = tid + 256 * n;  // 512 float4: As 64x8
      int rr = fi >> 3, dq = (fi & 7) * 4;
      *(float4*)&As[rr][dq] = *(const float4*)(A + (size_t)(r0 + rr) * 512 + d0 + dq);
    }
#pragma unroll
    for (int n = 0; n < 4; n++) {
      int fi = tid + 256 * n;  // 1024 float4: Ws 32x32
      int dd = fi >> 5, kq = (fi & 31) * 4;
      *(float4*)&Ws[dd][kq] = *(const float4*)(Wt + (size_t)(d0 + dd) * 128 + kq);
    }
    __syncthreads();
#pragma unroll 8
    for (int dd = 0; dd < 32; dd++) {
      float a[4], w[8];
#pragma unroll
      for (int i = 0; i < 4; i++) a[i] = As[ty + 16 * i][dd];
#pragma unroll
      for (int j = 0; j < 8; j++) w[j] = Ws[dd][tx + 16 * j];
#pragma unroll
      for (int i = 0; i < 4; i++)
#pragma unroll
        for (int j = 0; j < 8; j++) acc[i][j] = fmaf(a[i], w[j], acc[i][j]);
    }
    __syncthreads();
  }
  for (int i = 0; i < 4; i++) {
    float val[8];
#pragma unroll
    for (int j = 0; j < 8; j++) {
      val[j] = __fadd_rn(acc[i][j], bsh[tx + 16 * j]);
      sqb[ty][tx + 16 * j] = __fmul_rn(val[j], val[j]);
    }
    __syncthreads();
    if (tid < 128) {
      int row = tid >> 3, jj = tid & 7;
      float rr = sqb[row][jj];
      for (int blk = 1; blk < 16; blk++) rr += sqb[row][blk * 8 + jj];
      prb[row][jj] = rr;
    }
    __syncthreads();
    if (tid < 16) {
      float* p = prb[tid];
      float ss = ((p[0] + p[1]) + (p[2] + p[3])) + ((p[4] + p[5]) + (p[6] + p[7]));
      nshs[tid] = fmaxf(__fsqrt_rn(ss), L2EPSF);
    }
    __syncthreads();
    float nsh = nshs[ty];
    int r = r0 + ty + 16 * i;
#pragma unroll
    for (int j = 0; j < 8; j++)
      outp[(size_t)r * 128 + tx + 16 * j] = __fdiv_rn(val[j], nsh);
    __syncthreads();
  }
}

// ---------- scores 96x96 tiles: sc[(b*648+q)*648+s] = 30 * k-chain fmaf ------
__global__ __launch_bounds__(256) void k_scoret(const float* __restrict__ wqp,
                                                const float* __restrict__ wkp,
                                                float* __restrict__ sc) {
  int q0 = blockIdx.x * 96, s0 = blockIdx.y * 96, b = blockIdx.z;
  int tid = threadIdx.x, tx = tid & 15, ty = tid >> 4;
  __shared__ float QsT[32][97];   // kk-major (transposed)
  __shared__ float Ks[96][36];    // row-major
  float acc[6][6] = {};
  const float4 f40 = make_float4(0.f, 0.f, 0.f, 0.f);
  for (int k0 = 0; k0 < 128; k0 += 32) {
#pragma unroll
    for (int n = 0; n < 3; n++) {
      int fi = tid + 256 * n;  // 0..767
      int rr = fi >> 3, kq = (fi & 7) * 4;
      int q = q0 + rr;
      float4 v = (q < LL) ? *(const float4*)(wqp + ((size_t)q * 32 + b) * 128 + k0 + kq) : f40;
      QsT[kq + 0][rr] = v.x; QsT[kq + 1][rr] = v.y;
      QsT[kq + 2][rr] = v.z; QsT[kq + 3][rr] = v.w;
      int s = s0 + rr;
      float4 w = (s < MM) ? *(const float4*)(wkp + ((size_t)s * 32 + b) * 128 + k0 + kq) : f40;
      *(float4*)&Ks[rr][kq] = w;
    }
    __syncthreads();
#pragma unroll 8
    for (int kk = 0; kk < 32; kk++) {
      float a[6], w[6];
#pragma unroll
      for (int i = 0; i < 6; i++) a[i] = QsT[kk][ty + 16 * i];
#pragma unroll
      for (int j = 0; j < 6; j++) w[j] = Ks[tx + 16 * j][kk];
#pragma unroll
      for (int i = 0; i < 6; i++)
#pragma unroll
        for (int j = 0; j < 6; j++) acc[i][j] = fmaf(a[i], w[j], acc[i][j]);
    }
    __syncthreads();
  }
#pragma unroll
  for (int i = 0; i < 6; i++) {
    int q = q0 + ty + 16 * i;
    if (q >= LL) continue;
    float* orow = sc + ((size_t)b * LL + q) * MM;
#pragma unroll
    for (int j = 0; j < 6; j++) {
      int s = s0 + tx + 16 * j;
      if (s < MM) orow[s] = __fmul_rn(acc[i][j], TEMPF);
    }
  }
}

// ---------- softmax: identical math, pw648 via 64 independent lanes ----------
__global__ __launch_bounds__(256) void k_sm2(float* __restrict__ sc) {
  int row = blockIdx.x;
  float* p = sc + (size_t)row * MM;
  int t = threadIdx.x;
  __shared__ float red[256];
  __shared__ float es[MM];
  __shared__ float prc[64];
  __shared__ float ssum;
  float v0 = p[t], v1 = p[t + 256];
  bool h2 = t < (MM - 512);
  float v2 = h2 ? p[t + 512] : -3.0e38f;
  red[t] = fmaxf(fmaxf(v0, v1), v2);
  __syncthreads();
  for (int off = 128; off; off >>= 1) {
    if (t < off) red[t] = fmaxf(red[t], red[t + off]);
    __syncthreads();
  }
  float mx = red[0];
  float e0 = (float)exp((double)__fsub_rn(v0, mx));
  float e1 = (float)exp((double)__fsub_rn(v1, mx));
  float e2 = h2 ? (float)exp((double)__fsub_rn(v2, mx)) : 0.0f;
  es[t] = e0; es[t + 256] = e1;
  if (h2) es[t + 512] = e2;
  __syncthreads();
  if (t < 64) {
    int c = t >> 3, jj = t & 7;
    int base = c * 80, n = (c == 7) ? 88 : 80;
    float r = es[base + jj];
    for (int i = 8; i < n; i += 8) r += es[base + i + jj];
    prc[t] = r;
  }
  __syncthreads();
  if (t == 0) {
    float pc[8];
#pragma unroll
    for (int c = 0; c < 8; c++) {
      float* pp = prc + c * 8;
      pc[c] = ((pp[0] + pp[1]) + (pp[2] + pp[3])) + ((pp[4] + pp[5]) + (pp[6] + pp[7]));
    }
    float lsum = (pc[0] + pc[1]) + (pc[2] + pc[3]);
    float rsum = (pc[4] + pc[5]) + (pc[6] + pc[7]);
    ssum = lsum + rsum;
  }
  __syncthreads();
  float s = ssum;
  p[t] = __fdiv_rn(e0, s);
  p[t + 256] = __fdiv_rn(e1, s);
  if (h2) p[t + 512] = __fdiv_rn(e2, s);
}

// ---------- apply: Q=12, 256 threads, s_load_dwordx8 aff, float2 V -----------
// XCD-chunked swizzle: 1728 = 8 xcd * (4 b * 54 q-blocks)
// out[(q*32+b)][d] = s-chain fmaf (s ascending); mask[q*32+b] = s-chain vs ps
template <int DO_MASK>
__global__ __launch_bounds__(256) void k_applyg(const float* __restrict__ aff,
                                                const float* __restrict__ V,
                                                const float* __restrict__ ps,
                                                float* __restrict__ outp,
                                                float* __restrict__ msk) {
  int dd = blockIdx.x;             // 0..1727
  int xcd = dd & 7, j = dd >> 3;   // each XCD owns 4 batches
  int b = xcd * 4 + j / 54;
  int q0 = (j % 54) * 12;
  int tid = threadIdx.x;
  const float* abase = aff + ((size_t)b * LL + q0) * MM;
  const float* vbase = V + (size_t)b * 512 + tid * 2;
  float acc0[12] = {};
  float acc1[12] = {};
  for (int s8 = 0; s8 < 81; s8++) {
    float2 v0 = *(const float2*)(vbase + (size_t)(8 * s8 + 0) * 16384);
    float2 v1 = *(const float2*)(vbase + (size_t)(8 * s8 + 1) * 16384);
    float2 v2 = *(const float2*)(vbase + (size_t)(8 * s8 + 2) * 16384);
    float2 v3 = *(const float2*)(vbase + (size_t)(8 * s8 + 3) * 16384);
    float2 v4 = *(const float2*)(vbase + (size_t)(8 * s8 + 4) * 16384);
    float2 v5 = *(const float2*)(vbase + (size_t)(8 * s8 + 5) * 16384);
    float2 v6 = *(const float2*)(vbase + (size_t)(8 * s8 + 6) * 16384);
    float2 v7 = *(const float2*)(vbase + (size_t)(8 * s8 + 7) * 16384);
#pragma unroll
    for (int qq = 0; qq < 12; qq++) {
      f8v a8 = *(const f8v*)(abase + qq * MM + s8 * 8);  // wave-uniform 32B
      acc0[qq] = fmaf(a8[0], v0.x, acc0[qq]); acc1[qq] = fmaf(a8[0], v0.y, acc1[qq]);
      acc0[qq] = fmaf(a8[1], v1.x, acc0[qq]); acc1[qq] = fmaf(a8[1], v1.y, acc1[qq]);
      acc0[qq] = fmaf(a8[2], v2.x, acc0[qq]); acc1[qq] = fmaf(a8[2], v2.y, acc1[qq]);
      acc0[qq] = fmaf(a8[3], v3.x, acc0[qq]); acc1[qq] = fmaf(a8[3], v3.y, acc1[qq]);
      acc0[qq] = fmaf(a8[4], v4.x, acc0[qq]); acc1[qq] = fmaf(a8[4], v4.y, acc1[qq]);
      acc0[qq] = fmaf(a8[5], v5.x, acc0[qq]); acc1[qq] = fmaf(a8[5], v5.y, acc1[qq]);
      acc0[qq] = fmaf(a8[6], v6.x, acc0[qq]); acc1[qq] = fmaf(a8[6], v6.y, acc1[qq]);
      acc0[qq] = fmaf(a8[7], v7.x, acc0[qq]); acc1[qq] = fmaf(a8[7], v7.y, acc1[qq]);
    }
  }
#pragma unroll
  for (int qq = 0; qq < 12; qq++) {
    float2 r = make_float2(acc0[qq], acc1[qq]);
    *(float2*)(outp + ((size_t)(q0 + qq) * 32 + b) * 512 + tid * 2) = r;
  }
  if (DO_MASK && tid < 12) {
    const float* arow = abase + tid * MM;
    float a = 0.0f;
    for (int s = 0; s < MM; s++) a = fmaf(arow[s], ps[s * 32 + b], a);
    msk[(q0 + tid) * 32 + b] = a;
  }
}

// ---------- instance-norm stage A (verbatim) ---------------------------------
template <int MODE>
__global__ __launch_bounds__(128) void k_na(const float* __restrict__ x,
                                            const float* __restrict__ ao,
                                            const float* __restrict__ msk,
                                            const float* __restrict__ scu,
                                            const float* __restrict__ scv,
                                            float* __restrict__ tU,
                                            float* __restrict__ tV) {
  int s = blockIdx.x;
  int g = blockIdx.y;
  int i = g >> 5, b = g & 31;
  int l = i * HWX + s;
  size_t base = ((size_t)l * BB + b) * DD;
  int t = threadIdx.x;
  __shared__ float squ[DD];
  __shared__ float sqv[DD];
  __shared__ float pru[32];
  __shared__ float prv[32];
  float mk = 0.f, su = 0.f, sv = 0.f;
  if (MODE >= 2) mk = msk[l * BB + b];
  if (MODE == 3) { su = scu[g]; sv = scv[g]; }
  for (int d = t; d < DD; d += 128) {
    float xx = x[base + d];
    if (MODE == 1) {
      float y = __fadd_rn(xx, ao[base + d]);
      squ[d] = __fmul_rn(y, y);
    } else if (MODE == 2) {
      float u = __fmul_rn(xx, mk);
      float v = __fadd_rn(xx, ao[base + d]);
      squ[d] = __fmul_rn(u, u);
      sqv[d] = __fmul_rn(v, v);
    } else {
      float u = __fmul_rn(xx, mk);
      float v = __fadd_rn(xx, ao[base + d]);
      float t2 = __fmul_rn(u, su);
      float t4 = __fmul_rn(v, sv);
      float w = __fadd_rn(t2, t4);
      squ[d] = __fmul_rn(w, w);
    }
  }
  __syncthreads();
  if (t < 32) {
    int c = t >> 3, jj = t & 7, b0 = c * 128;
    float r = squ[b0 + jj];
    for (int blk = 1; blk < 16; blk++) r += squ[b0 + blk * 8 + jj];
    pru[t] = r;
    if (MODE == 2) {
      float r2 = sqv[b0 + jj];
      for (int blk = 1; blk < 16; blk++) r2 += sqv[b0 + blk * 8 + jj];
      prv[t] = r2;
    }
  }
  __syncthreads();
  if (t == 0) {
    float cc[4];
    for (int c = 0; c < 4; c++)
      cc[c] = ((pru[c * 8] + pru[c * 8 + 1]) + (pru[c * 8 + 2] + pru[c * 8 + 3])) +
              ((pru[c * 8 + 4] + pru[c * 8 + 5]) + (pru[c * 8 + 6] + pru[c * 8 + 7]));
    tU[g * HWX + s] = (cc[0] + cc[1]) + (cc[2] + cc[3]);
    if (MODE == 2) {
      for (int c = 0; c < 4; c++)
        cc[c] = ((prv[c * 8] + prv[c * 8 + 1]) + (prv[c * 8 + 2] + prv[c * 8 + 3])) +
                ((prv[c * 8 + 4] + prv[c * 8 + 5]) + (prv[c * 8 + 6] + prv[c * 8 + 7]));
      tV[g * HWX + s] = (cc[0] + cc[1]) + (cc[2] + cc[3]);
    }
  }
}

__global__ void k_fin1(const float* __restrict__ tU, float* __restrict__ scl) {
  int g = threadIdx.x;
  float ss = 0.0f;
  for (int s4 = 0; s4 < 81; s4++) {
    float4 t = *(const float4*)(tU + g * HWX + s4 * 4);
    ss += t.x; ss += t.y; ss += t.z; ss += t.w;
  }
  scl[g] = __fmul_rn(NSDF, __fsqrt_rn(__fdiv_rn(DHWF, __fadd_rn(ss, NEPSF))));
}

__global__ void k_fin2(const float* __restrict__ tU, const float* __restrict__ tV,
                       float* __restrict__ scu, float* __restrict__ scv) {
  int g = threadIdx.x;
  float su = 0.0f, sv = 0.0f;
  for (int s4 = 0; s4 < 81; s4++) {
    float4 t = *(const float4*)(tU + g * HWX + s4 * 4);
    float4 t2 = *(const float4*)(tV + g * HWX + s4 * 4);
    su += t.x; su += t.y; su += t.z; su += t.w;
    sv += t2.x; sv += t2.y; sv += t2.z; sv += t2.w;
  }
  scu[g] = __fmul_rn(NSDF, __fsqrt_rn(__fdiv_rn(DHWF, __fadd_rn(su, NEPSF))));
  scv[g] = __fmul_rn(NSDF, __fsqrt_rn(__fdiv_rn(DHWF, __fadd_rn(sv, NEPSF))));
}

__global__ void k_a1(float* __restrict__ x, const float* __restrict__ ao,
                     const float* __restrict__ scl) {
  size_t idx = (size_t)blockIdx.x * 256 + threadIdx.x;
  int r = (int)(idx >> 9);
  int l = r >> 5, b = r & 31;
  int g = (l / HWX) * BB + b;
  x[idx] = __fmul_rn(__fadd_rn(x[idx], ao[idx]), scl[g]);
}

// ---------- a2 (+ optional fused next-layer addpe, bit-identical chain) ------
template <int ADDPE>
__global__ void k_a2(float* __restrict__ x, const float* __restrict__ ao,
                     const float* __restrict__ msk, const float* __restrict__ scu,
                     const float* __restrict__ scv, const float* __restrict__ scw,
                     const float* __restrict__ pe) {
  size_t idx = (size_t)blockIdx.x * 256 + threadIdx.x;
  int r = (int)(idx >> 9);
  int l = r >> 5, b = r & 31;
  int g = (l / HWX) * BB + b;
  float mk = msk[l * BB + b];
  float xx = x[idx];
  float u = __fmul_rn(xx, mk);
  float v = __fadd_rn(xx, ao[idx]);
  float t2 = __fmul_rn(u, scu[g]);
  float t4 = __fmul_rn(v, scv[g]);
  float w = __fadd_rn(t2, t4);
  float res = __fmul_rn(w, scw[g]);
  if (ADDPE) {
    int d = (int)(idx & 511);
    int i = l / HWX, s = l % HWX;
    float t = __fmul_rn(pe[((size_t)(i * BB + b) * DD + d) * HWX + s], 0.001f);
    res = __fadd_rn(res, t);
  }
  x[idx] = res;
}

// ---------- outputs ----------------------------------------------------------
__global__ void k_o0(const float* __restrict__ x, float* __restrict__ out) {
  size_t idx = (size_t)blockIdx.x * 256 + threadIdx.x;
  out[idx] = x[idx];
}

__global__ void k_o1(const float* __restrict__ x, float* __restrict__ out1) {
  size_t idx = (size_t)blockIdx.x * 256 + threadIdx.x;
  int s = (int)(idx % HWX);
  int d = (int)((idx / HWX) & 511);
  int ib = (int)(idx / ((size_t)HWX * DD));
  int i = ib >> 5, b = ib & 31;
  int l = i * HWX + s;
  out1[idx] = x[((size_t)l * BB + b) * DD + d];
}

// ---------------------------------------------------------------------------
extern "C" void kernel_launch(void* const* d_in, const int* in_sizes, int n_in,
                              void* d_out, int out_size, void* d_ws, size_t ws_size,
                              hipStream_t stream) {
  const float* tgt = (const float*)d_in[0];
  const float* pe  = (const float*)d_in[1];
  const float* mem = (const float*)d_in[2];
  const float* pos = (const float*)d_in[3];
  const float* Wks = (const float*)d_in[4];
  const float* bks = (const float*)d_in[5];
  const float* Wkc = (const float*)d_in[6];
  const float* bkc = (const float*)d_in[7];
  float* out = (float*)d_out;

  // 50,810,112 floats = 203,240,448 bytes
  if (ws_size < (size_t)203240448) return;
  float* f = (float*)d_ws;
  float* x    = f;                  // 10,616,832  [l,b,d]
  float* ao   = f + 10616832;       // 10,616,832
  float* memp = f + 21233664;       // 10,616,832
  float* wq   = f + 31850496;       //  2,654,208  [l,b,k]
  float* wkm  = f + 34504704;       //  2,654,208
  float* sc   = f + 37158912;       // 13,436,928  [b,q,s]
  float* msk  = f + 50595840;       //     20,736  [q,b]
  float* ps   = f + 50616576;       //     20,736  [l,b]
  float* tU   = f + 50637312;       //     20,736
  float* tV   = f + 50658048;       //     20,736
  float* scl  = f + 50678784;       //        256
  float* scu  = scl + 64;
  float* scv  = scl + 128;
  float* scw  = scl + 192;
  float* Wst  = f + 50679040;       //     65,536  [d,k]
  float* Wct  = f + 50744576;       //     65,536

  k_wt<<<256, 256, 0, stream>>>(Wks, Wst);
  k_wt<<<256, 256, 0, stream>>>(Wkc, Wct);
  k_flat<<<41472, 256, 0, stream>>>(tgt, pe, x);   // layer-0 addpe fused
  k_pos<<<81, 256, 0, stream>>>(pos, ps);
  k_memp<<<41472, 256, 0, stream>>>(mem, ps, memp);
  // loop-invariant cross keys from memory
  k_projt<<<324, 256, 0, stream>>>(mem, Wct, bkc, wkm);

  dim3 scg(7, 7, 32);
  dim3 nag(324, 64);
  for (int l = 0; l < 6; l++) {
    // --- self-attention (q=k=v=x) --- (x already has pe added)
    k_projt<<<324, 256, 0, stream>>>(x, Wst, bks, wq);
    k_scoret<<<scg, 256, 0, stream>>>(wq, wq, sc);
    k_sm2<<<20736, 256, 0, stream>>>(sc);
    k_applyg<0><<<1728, 256, 0, stream>>>(sc, x, nullptr, ao, nullptr);
    k_na<1><<<nag, 128, 0, stream>>>(x, ao, nullptr, nullptr, nullptr, tU, nullptr);
    k_fin1<<<1, 64, 0, stream>>>(tU, scl);
    k_a1<<<41472, 256, 0, stream>>>(x, ao, scl);
    // --- cross-attention: shared softmax; mask in applyg 12-lane tail ---
    k_projt<<<324, 256, 0, stream>>>(x, Wct, bkc, wq);
    k_scoret<<<scg, 256, 0, stream>>>(wq, wkm, sc);
    k_sm2<<<20736, 256, 0, stream>>>(sc);
    k_applyg<1><<<1728, 256, 0, stream>>>(sc, memp, ps, ao, msk);
    k_na<2><<<nag, 128, 0, stream>>>(x, ao, msk, nullptr, nullptr, tU, tV);
    k_fin2<<<1, 64, 0, stream>>>(tU, tV, scu, scv);
    k_na<3><<<nag, 128, 0, stream>>>(x, ao, msk, scu, scv, tU, nullptr);
    k_fin1<<<1, 64, 0, stream>>>(tU, scw);
    if (l < 5)
      k_a2<1><<<41472, 256, 0, stream>>>(x, ao, msk, scu, scv, scw, pe);
    else
      k_a2<0><<<41472, 256, 0, stream>>>(x, ao, msk, scu, scv, scw, nullptr);
  }

  k_o0<<<41472, 256, 0, stream>>>(x, out);
  k_o1<<<41472, 256, 0, stream>>>(x, out + (size_t)LL * BB * DD);
}

// Round 19
// 5487.251 us; speedup vs baseline: 1.0902x; 1.0151x over previous
//
#include <hip/hip_runtime.h>
#include <math.h>

#define NI  2
#define BB  32
#define DD  512
#define HWX 324
#define LL  648
#define MM  648
#define KX  128

#define TEMPF  30.0f
#define NEPSF  1e-5f
#define L2EPSF 1e-12f
#define DHWF   165888.0f
#define NSDF   0.011048543456039806f

typedef float f8v __attribute__((ext_vector_type(8)));

// ---------- staging: x = flat(tgt) + 0.001*flat(pe)  (layer-0 addpe fused) ---
__global__ void k_flat(const float* __restrict__ src, const float* __restrict__ pe,
                       float* __restrict__ x) {
  size_t idx = (size_t)blockIdx.x * 256 + threadIdx.x;
  int r = (int)(idx >> 9), d = (int)(idx & 511);
  int l = r >> 5, b = r & 31;
  int i = l / HWX, s = l % HWX;
  size_t sidx = ((size_t)(i * BB + b) * DD + d) * HWX + s;
  float v = src[sidx];
  float t = __fmul_rn(pe[sidx], 0.001f);
  x[idx] = __fadd_rn(v, t);
}

__global__ void k_pos(const float* __restrict__ pos, float* __restrict__ ps) {
  int idx = blockIdx.x * 256 + threadIdx.x;  // 20736
  int l = idx >> 5, b = idx & 31;
  int j = l / HWX, s = l % HWX;
  ps[idx] = pos[((size_t)(j * BB + b)) * HWX + s];
}

__global__ void k_memp(const float* __restrict__ mem, const float* __restrict__ ps,
                       float* __restrict__ memp) {
  size_t idx = (size_t)blockIdx.x * 256 + threadIdx.x;
  memp[idx] = __fmul_rn(mem[idx], ps[idx >> 9]);
}

__global__ void k_wt(const float* __restrict__ W, float* __restrict__ Wt) {
  int idx = blockIdx.x * 256 + threadIdx.x;  // 65536: dst [d][k]
  int k = idx & 127, d = idx >> 7;
  Wt[idx] = W[(size_t)k * DD + d];
}

// ---------- projection + bias + l2norm: 64-row tiles, 256 thr (chains = r7) --
__global__ __launch_bounds__(256) void k_projt(const float* __restrict__ A,
                                               const float* __restrict__ Wt,
                                               const float* __restrict__ bias,
                                               float* __restrict__ outp) {
  int r0 = blockIdx.x * 64;   // grid 324
  int tid = threadIdx.x, tx = tid & 15, ty = tid >> 4;  // ty 0..15
  __shared__ float As[64][36];
  __shared__ float Ws[32][132];
  __shared__ float bsh[128];
  __shared__ float sqb[16][129];
  __shared__ float prb[16][8];
  __shared__ float nshs[16];
  if (tid < 128) bsh[tid] = bias[tid];
  float acc[4][8] = {};
  for (int d0 = 0; d0 < 512; d0 += 32) {
#pragma unroll
    for (int n = 0; n < 2; n++) {
      int fi = tid + 256 * n;  // 512 float4: As 64x8
      int rr = fi >> 3, dq = (fi & 7) * 4;
      *(float4*)&As[rr][dq] = *(const float4*)(A + (size_t)(r0 + rr) * 512 + d0 + dq);
    }
#pragma unroll
    for (int n = 0; n < 4; n++) {
      int fi = tid + 256 * n;  // 1024 float4: Ws 32x32
      int dd = fi >> 5, kq = (fi & 31) * 4;
      *(float4*)&Ws[dd][kq] = *(const float4*)(Wt + (size_t)(d0 + dd) * 128 + kq);
    }
    __syncthreads();
#pragma unroll 8
    for (int dd = 0; dd < 32; dd++) {
      float a[4], w[8];
#pragma unroll
      for (int i = 0; i < 4; i++) a[i] = As[ty + 16 * i][dd];
#pragma unroll
      for (int j = 0; j < 8; j++) w[j] = Ws[dd][tx + 16 * j];
#pragma unroll
      for (int i = 0; i < 4; i++)
#pragma unroll
        for (int j = 0; j < 8; j++) acc[i][j] = fmaf(a[i], w[j], acc[i][j]);
    }
    __syncthreads();
  }
  for (int i = 0; i < 4; i++) {
    float val[8];
#pragma unroll
    for (int j = 0; j < 8; j++) {
      val[j] = __fadd_rn(acc[i][j], bsh[tx + 16 * j]);
      sqb[ty][tx + 16 * j] = __fmul_rn(val[j], val[j]);
    }
    __syncthreads();
    if (tid < 128) {
      int row = tid >> 3, jj = tid & 7;
      float rr = sqb[row][jj];
      for (int blk = 1; blk < 16; blk++) rr += sqb[row][blk * 8 + jj];
      prb[row][jj] = rr;
    }
    __syncthreads();
    if (tid < 16) {
      float* p = prb[tid];
      float ss = ((p[0] + p[1]) + (p[2] + p[3])) + ((p[4] + p[5]) + (p[6] + p[7]));
      nshs[tid] = fmaxf(__fsqrt_rn(ss), L2EPSF);
    }
    __syncthreads();
    float nsh = nshs[ty];
    int r = r0 + ty + 16 * i;
#pragma unroll
    for (int j = 0; j < 8; j++)
      outp[(size_t)r * 128 + tx + 16 * j] = __fdiv_rn(val[j], nsh);
    __syncthreads();
  }
}

// ---------- scores 96x96 tiles: sc[(b*648+q)*648+s] = 30 * k-chain fmaf ------
// SYM=1: self-attention upper-triangle tiles only; mirror write (bit-identical
// by fmaf commutativity: sum_k wq[q][k]*wq[s][k] chain == transposed chain).
template <int SYM>
__global__ __launch_bounds__(256) void k_scoret(const float* __restrict__ wqp,
                                                const float* __restrict__ wkp,
                                                float* __restrict__ sc) {
  int q0, s0, b;
  if (SYM) {
    int p = blockIdx.x;  // 0..27 upper-triangle pairs of 7 tiles
    b = blockIdx.y;
    int qi = 0;
    while (p >= 7 - qi) { p -= 7 - qi; qi++; }
    int si = qi + p;
    q0 = qi * 96; s0 = si * 96;
  } else {
    q0 = blockIdx.x * 96; s0 = blockIdx.y * 96; b = blockIdx.z;
  }
  int tid = threadIdx.x, tx = tid & 15, ty = tid >> 4;
  __shared__ float QsT[32][97];   // kk-major (transposed)
  __shared__ float Ks[96][36];    // row-major
  float acc[6][6] = {};
  const float4 f40 = make_float4(0.f, 0.f, 0.f, 0.f);
  for (int k0 = 0; k0 < 128; k0 += 32) {
#pragma unroll
    for (int n = 0; n < 3; n++) {
      int fi = tid + 256 * n;  // 0..767
      int rr = fi >> 3, kq = (fi & 7) * 4;
      int q = q0 + rr;
      float4 v = (q < LL) ? *(const float4*)(wqp + ((size_t)q * 32 + b) * 128 + k0 + kq) : f40;
      QsT[kq + 0][rr] = v.x; QsT[kq + 1][rr] = v.y;
      QsT[kq + 2][rr] = v.z; QsT[kq + 3][rr] = v.w;
      int s = s0 + rr;
      float4 w = (s < MM) ? *(const float4*)(wkp + ((size_t)s * 32 + b) * 128 + k0 + kq) : f40;
      *(float4*)&Ks[rr][kq] = w;
    }
    __syncthreads();
#pragma unroll 8
    for (int kk = 0; kk < 32; kk++) {
      float a[6], w[6];
#pragma unroll
      for (int i = 0; i < 6; i++) a[i] = QsT[kk][ty + 16 * i];
#pragma unroll
      for (int j = 0; j < 6; j++) w[j] = Ks[tx + 16 * j][kk];
#pragma unroll
      for (int i = 0; i < 6; i++)
#pragma unroll
        for (int j = 0; j < 6; j++) acc[i][j] = fmaf(a[i], w[j], acc[i][j]);
    }
    __syncthreads();
  }
#pragma unroll
  for (int i = 0; i < 6; i++) {
    int q = q0 + ty + 16 * i;
    if (q >= LL) continue;
    float* orow = sc + ((size_t)b * LL + q) * MM;
#pragma unroll
    for (int j = 0; j < 6; j++) {
      int s = s0 + tx + 16 * j;
      if (s < MM) orow[s] = __fmul_rn(acc[i][j], TEMPF);
    }
  }
  if (SYM && s0 != q0) {  // mirror write: sc[b][s][q] = same bit value
#pragma unroll
    for (int i = 0; i < 6; i++) {
      int q = q0 + ty + 16 * i;
      if (q >= LL) continue;
#pragma unroll
      for (int j = 0; j < 6; j++) {
        int s = s0 + tx + 16 * j;
        if (s < MM)
          sc[((size_t)b * LL + s) * MM + q] = __fmul_rn(acc[i][j], TEMPF);
      }
    }
  }
}

// ---------- softmax: identical math, pw648 via 64 independent lanes ----------
__global__ __launch_bounds__(256) void k_sm2(float* __restrict__ sc) {
  int row = blockIdx.x;
  float* p = sc + (size_t)row * MM;
  int t = threadIdx.x;
  __shared__ float red[256];
  __shared__ float es[MM];
  __shared__ float prc[64];
  __shared__ float ssum;
  float v0 = p[t], v1 = p[t + 256];
  bool h2 = t < (MM - 512);
  float v2 = h2 ? p[t + 512] : -3.0e38f;
  red[t] = fmaxf(fmaxf(v0, v1), v2);
  __syncthreads();
  for (int off = 128; off; off >>= 1) {
    if (t < off) red[t] = fmaxf(red[t], red[t + off]);
    __syncthreads();
  }
  float mx = red[0];
  float e0 = (float)exp((double)__fsub_rn(v0, mx));
  float e1 = (float)exp((double)__fsub_rn(v1, mx));
  float e2 = h2 ? (float)exp((double)__fsub_rn(v2, mx)) : 0.0f;
  es[t] = e0; es[t + 256] = e1;
  if (h2) es[t + 512] = e2;
  __syncthreads();
  if (t < 64) {
    int c = t >> 3, jj = t & 7;
    int base = c * 80, n = (c == 7) ? 88 : 80;
    float r = es[base + jj];
    for (int i = 8; i < n; i += 8) r += es[base + i + jj];
    prc[t] = r;
  }
  __syncthreads();
  if (t == 0) {
    float pc[8];
#pragma unroll
    for (int c = 0; c < 8; c++) {
      float* pp = prc + c * 8;
      pc[c] = ((pp[0] + pp[1]) + (pp[2] + pp[3])) + ((pp[4] + pp[5]) + (pp[6] + pp[7]));
    }
    float lsum = (pc[0] + pc[1]) + (pc[2] + pc[3]);
    float rsum = (pc[4] + pc[5]) + (pc[6] + pc[7]);
    ssum = lsum + rsum;
  }
  __syncthreads();
  float s = ssum;
  p[t] = __fdiv_rn(e0, s);
  p[t + 256] = __fdiv_rn(e1, s);
  if (h2) p[t + 512] = __fdiv_rn(e2, s);
}

// ---------- apply: Q=12, 256 threads, s_load_dwordx8 aff, float2 V -----------
// XCD-chunked swizzle: 1728 = 8 xcd * (4 b * 54 q-blocks)
// out[(q*32+b)][d] = s-chain fmaf (s ascending); mask[q*32+b] = s-chain vs ps
template <int DO_MASK>
__global__ __launch_bounds__(256) void k_applyg(const float* __restrict__ aff,
                                                const float* __restrict__ V,
                                                const float* __restrict__ ps,
                                                float* __restrict__ outp,
                                                float* __restrict__ msk) {
  int dd = blockIdx.x;             // 0..1727
  int xcd = dd & 7, j = dd >> 3;   // each XCD owns 4 batches
  int b = xcd * 4 + j / 54;
  int q0 = (j % 54) * 12;
  int tid = threadIdx.x;
  const float* abase = aff + ((size_t)b * LL + q0) * MM;
  const float* vbase = V + (size_t)b * 512 + tid * 2;
  float acc0[12] = {};
  float acc1[12] = {};
  for (int s8 = 0; s8 < 81; s8++) {
    float2 v0 = *(const float2*)(vbase + (size_t)(8 * s8 + 0) * 16384);
    float2 v1 = *(const float2*)(vbase + (size_t)(8 * s8 + 1) * 16384);
    float2 v2 = *(const float2*)(vbase + (size_t)(8 * s8 + 2) * 16384);
    float2 v3 = *(const float2*)(vbase + (size_t)(8 * s8 + 3) * 16384);
    float2 v4 = *(const float2*)(vbase + (size_t)(8 * s8 + 4) * 16384);
    float2 v5 = *(const float2*)(vbase + (size_t)(8 * s8 + 5) * 16384);
    float2 v6 = *(const float2*)(vbase + (size_t)(8 * s8 + 6) * 16384);
    float2 v7 = *(const float2*)(vbase + (size_t)(8 * s8 + 7) * 16384);
#pragma unroll
    for (int qq = 0; qq < 12; qq++) {
      f8v a8 = *(const f8v*)(abase + qq * MM + s8 * 8);  // wave-uniform 32B
      acc0[qq] = fmaf(a8[0], v0.x, acc0[qq]); acc1[qq] = fmaf(a8[0], v0.y, acc1[qq]);
      acc0[qq] = fmaf(a8[1], v1.x, acc0[qq]); acc1[qq] = fmaf(a8[1], v1.y, acc1[qq]);
      acc0[qq] = fmaf(a8[2], v2.x, acc0[qq]); acc1[qq] = fmaf(a8[2], v2.y, acc1[qq]);
      acc0[qq] = fmaf(a8[3], v3.x, acc0[qq]); acc1[qq] = fmaf(a8[3], v3.y, acc1[qq]);
      acc0[qq] = fmaf(a8[4], v4.x, acc0[qq]); acc1[qq] = fmaf(a8[4], v4.y, acc1[qq]);
      acc0[qq] = fmaf(a8[5], v5.x, acc0[qq]); acc1[qq] = fmaf(a8[5], v5.y, acc1[qq]);
      acc0[qq] = fmaf(a8[6], v6.x, acc0[qq]); acc1[qq] = fmaf(a8[6], v6.y, acc1[qq]);
      acc0[qq] = fmaf(a8[7], v7.x, acc0[qq]); acc1[qq] = fmaf(a8[7], v7.y, acc1[qq]);
    }
  }
#pragma unroll
  for (int qq = 0; qq < 12; qq++) {
    float2 r = make_float2(acc0[qq], acc1[qq]);
    *(float2*)(outp + ((size_t)(q0 + qq) * 32 + b) * 512 + tid * 2) = r;
  }
  if (DO_MASK && tid < 12) {
    const float* arow = abase + tid * MM;
    float a = 0.0f;
    for (int s = 0; s < MM; s++) a = fmaf(arow[s], ps[s * 32 + b], a);
    msk[(q0 + tid) * 32 + b] = a;
  }
}

// ---------- instance-norm stage A (verbatim) ---------------------------------
template <int MODE>
__global__ __launch_bounds__(128) void k_na(const float* __restrict__ x,
                                            const float* __restrict__ ao,
                                            const float* __restrict__ msk,
                                            const float* __restrict__ scu,
                                            const float* __restrict__ scv,
                                            float* __restrict__ tU,
                                            float* __restrict__ tV) {
  int s = blockIdx.x;
  int g = blockIdx.y;
  int i = g >> 5, b = g & 31;
  int l = i * HWX + s;
  size_t base = ((size_t)l * BB + b) * DD;
  int t = threadIdx.x;
  __shared__ float squ[DD];
  __shared__ float sqv[DD];
  __shared__ float pru[32];
  __shared__ float prv[32];
  float mk = 0.f, su = 0.f, sv = 0.f;
  if (MODE >= 2) mk = msk[l * BB + b];
  if (MODE == 3) { su = scu[g]; sv = scv[g]; }
  for (int d = t; d < DD; d += 128) {
    float xx = x[base + d];
    if (MODE == 1) {
      float y = __fadd_rn(xx, ao[base + d]);
      squ[d] = __fmul_rn(y, y);
    } else if (MODE == 2) {
      float u = __fmul_rn(xx, mk);
      float v = __fadd_rn(xx, ao[base + d]);
      squ[d] = __fmul_rn(u, u);
      sqv[d] = __fmul_rn(v, v);
    } else {
      float u = __fmul_rn(xx, mk);
      float v = __fadd_rn(xx, ao[base + d]);
      float t2 = __fmul_rn(u, su);
      float t4 = __fmul_rn(v, sv);
      float w = __fadd_rn(t2, t4);
      squ[d] = __fmul_rn(w, w);
    }
  }
  __syncthreads();
  if (t < 32) {
    int c = t >> 3, jj = t & 7, b0 = c * 128;
    float r = squ[b0 + jj];
    for (int blk = 1; blk < 16; blk++) r += squ[b0 + blk * 8 + jj];
    pru[t] = r;
    if (MODE == 2) {
      float r2 = sqv[b0 + jj];
      for (int blk = 1; blk < 16; blk++) r2 += sqv[b0 + blk * 8 + jj];
      prv[t] = r2;
    }
  }
  __syncthreads();
  if (t == 0) {
    float cc[4];
    for (int c = 0; c < 4; c++)
      cc[c] = ((pru[c * 8] + pru[c * 8 + 1]) + (pru[c * 8 + 2] + pru[c * 8 + 3])) +
              ((pru[c * 8 + 4] + pru[c * 8 + 5]) + (pru[c * 8 + 6] + pru[c * 8 + 7]));
    tU[g * HWX + s] = (cc[0] + cc[1]) + (cc[2] + cc[3]);
    if (MODE == 2) {
      for (int c = 0; c < 4; c++)
        cc[c] = ((prv[c * 8] + prv[c * 8 + 1]) + (prv[c * 8 + 2] + prv[c * 8 + 3])) +
                ((prv[c * 8 + 4] + prv[c * 8 + 5]) + (prv[c * 8 + 6] + prv[c * 8 + 7]));
      tV[g * HWX + s] = (cc[0] + cc[1]) + (cc[2] + cc[3]);
    }
  }
}

__global__ void k_fin1(const float* __restrict__ tU, float* __restrict__ scl) {
  int g = threadIdx.x;
  float ss = 0.0f;
  for (int s4 = 0; s4 < 81; s4++) {
    float4 t = *(const float4*)(tU + g * HWX + s4 * 4);
    ss += t.x; ss += t.y; ss += t.z; ss += t.w;
  }
  scl[g] = __fmul_rn(NSDF, __fsqrt_rn(__fdiv_rn(DHWF, __fadd_rn(ss, NEPSF))));
}

__global__ void k_fin2(const float* __restrict__ tU, const float* __restrict__ tV,
                       float* __restrict__ scu, float* __restrict__ scv) {
  int g = threadIdx.x;
  float su = 0.0f, sv = 0.0f;
  for (int s4 = 0; s4 < 81; s4++) {
    float4 t = *(const float4*)(tU + g * HWX + s4 * 4);
    float4 t2 = *(const float4*)(tV + g * HWX + s4 * 4);
    su += t.x; su += t.y; su += t.z; su += t.w;
    sv += t2.x; sv += t2.y; sv += t2.z; sv += t2.w;
  }
  scu[g] = __fmul_rn(NSDF, __fsqrt_rn(__fdiv_rn(DHWF, __fadd_rn(su, NEPSF))));
  scv[g] = __fmul_rn(NSDF, __fsqrt_rn(__fdiv_rn(DHWF, __fadd_rn(sv, NEPSF))));
}

__global__ void k_a1(float* __restrict__ x, const float* __restrict__ ao,
                     const float* __restrict__ scl) {
  size_t idx = (size_t)blockIdx.x * 256 + threadIdx.x;
  int r = (int)(idx >> 9);
  int l = r >> 5, b = r & 31;
  int g = (l / HWX) * BB + b;
  x[idx] = __fmul_rn(__fadd_rn(x[idx], ao[idx]), scl[g]);
}

// ---------- a2 (+ optional fused next-layer addpe, bit-identical chain) ------
template <int ADDPE>
__global__ void k_a2(float* __restrict__ x, const float* __restrict__ ao,
                     const float* __restrict__ msk, const float* __restrict__ scu,
                     const float* __restrict__ scv, const float* __restrict__ scw,
                     const float* __restrict__ pe) {
  size_t idx = (size_t)blockIdx.x * 256 + threadIdx.x;
  int r = (int)(idx >> 9);
  int l = r >> 5, b = r & 31;
  int g = (l / HWX) * BB + b;
  float mk = msk[l * BB + b];
  float xx = x[idx];
  float u = __fmul_rn(xx, mk);
  float v = __fadd_rn(xx, ao[idx]);
  float t2 = __fmul_rn(u, scu[g]);
  float t4 = __fmul_rn(v, scv[g]);
  float w = __fadd_rn(t2, t4);
  float res = __fmul_rn(w, scw[g]);
  if (ADDPE) {
    int d = (int)(idx & 511);
    int i = l / HWX, s = l % HWX;
    float t = __fmul_rn(pe[((size_t)(i * BB + b) * DD + d) * HWX + s], 0.001f);
    res = __fadd_rn(res, t);
  }
  x[idx] = res;
}

// ---------- outputs ----------------------------------------------------------
__global__ void k_o0(const float* __restrict__ x, float* __restrict__ out) {
  size_t idx = (size_t)blockIdx.x * 256 + threadIdx.x;
  out[idx] = x[idx];
}

__global__ void k_o1(const float* __restrict__ x, float* __restrict__ out1) {
  size_t idx = (size_t)blockIdx.x * 256 + threadIdx.x;
  int s = (int)(idx % HWX);
  int d = (int)((idx / HWX) & 511);
  int ib = (int)(idx / ((size_t)HWX * DD));
  int i = ib >> 5, b = ib & 31;
  int l = i * HWX + s;
  out1[idx] = x[((size_t)l * BB + b) * DD + d];
}

// ---------------------------------------------------------------------------
extern "C" void kernel_launch(void* const* d_in, const int* in_sizes, int n_in,
                              void* d_out, int out_size, void* d_ws, size_t ws_size,
                              hipStream_t stream) {
  const float* tgt = (const float*)d_in[0];
  const float* pe  = (const float*)d_in[1];
  const float* mem = (const float*)d_in[2];
  const float* pos = (const float*)d_in[3];
  const float* Wks = (const float*)d_in[4];
  const float* bks = (const float*)d_in[5];
  const float* Wkc = (const float*)d_in[6];
  const float* bkc = (const float*)d_in[7];
  float* out = (float*)d_out;

  // 50,810,112 floats = 203,240,448 bytes
  if (ws_size < (size_t)203240448) return;
  float* f = (float*)d_ws;
  float* x    = f;                  // 10,616,832  [l,b,d]
  float* ao   = f + 10616832;       // 10,616,832
  float* memp = f + 21233664;       // 10,616,832
  float* wq   = f + 31850496;       //  2,654,208  [l,b,k]
  float* wkm  = f + 34504704;       //  2,654,208
  float* sc   = f + 37158912;       // 13,436,928  [b,q,s]
  float* msk  = f + 50595840;       //     20,736  [q,b]
  float* ps   = f + 50616576;       //     20,736  [l,b]
  float* tU   = f + 50637312;       //     20,736
  float* tV   = f + 50658048;       //     20,736
  float* scl  = f + 50678784;       //        256
  float* scu  = scl + 64;
  float* scv  = scl + 128;
  float* scw  = scl + 192;
  float* Wst  = f + 50679040;       //     65,536  [d,k]
  float* Wct  = f + 50744576;       //     65,536

  k_wt<<<256, 256, 0, stream>>>(Wks, Wst);
  k_wt<<<256, 256, 0, stream>>>(Wkc, Wct);
  k_flat<<<41472, 256, 0, stream>>>(tgt, pe, x);   // layer-0 addpe fused
  k_pos<<<81, 256, 0, stream>>>(pos, ps);
  k_memp<<<41472, 256, 0, stream>>>(mem, ps, memp);
  // loop-invariant cross keys from memory
  k_projt<<<324, 256, 0, stream>>>(mem, Wct, bkc, wkm);

  dim3 scgSym(28, 32);
  dim3 scg(7, 7, 32);
  dim3 nag(324, 64);
  for (int l = 0; l < 6; l++) {
    // --- self-attention (q=k=v=x): symmetric scores, upper-triangle tiles ---
    k_projt<<<324, 256, 0, stream>>>(x, Wst, bks, wq);
    k_scoret<1><<<scgSym, 256, 0, stream>>>(wq, wq, sc);
    k_sm2<<<20736, 256, 0, stream>>>(sc);
    k_applyg<0><<<1728, 256, 0, stream>>>(sc, x, nullptr, ao, nullptr);
    k_na<1><<<nag, 128, 0, stream>>>(x, ao, nullptr, nullptr, nullptr, tU, nullptr);
    k_fin1<<<1, 64, 0, stream>>>(tU, scl);
    k_a1<<<41472, 256, 0, stream>>>(x, ao, scl);
    // --- cross-attention: shared softmax; mask in applyg 12-lane tail ---
    k_projt<<<324, 256, 0, stream>>>(x, Wct, bkc, wq);
    k_scoret<0><<<scg, 256, 0, stream>>>(wq, wkm, sc);
    k_sm2<<<20736, 256, 0, stream>>>(sc);
    k_applyg<1><<<1728, 256, 0, stream>>>(sc, memp, ps, ao, msk);
    k_na<2><<<nag, 128, 0, stream>>>(x, ao, msk, nullptr, nullptr, tU, tV);
    k_fin2<<<1, 64, 0, stream>>>(tU, tV, scu, scv);
    k_na<3><<<nag, 128, 0, stream>>>(x, ao, msk, scu, scv, tU, nullptr);
    k_fin1<<<1, 64, 0, stream>>>(tU, scw);
    if (l < 5)
      k_a2<1><<<41472, 256, 0, stream>>>(x, ao, msk, scu, scv, scw, pe);
    else
      k_a2<0><<<41472, 256, 0, stream>>>(x, ao, msk, scu, scv, scw, nullptr);
  }

  k_o0<<<41472, 256, 0, stream>>>(x, out);
  k_o1<<<41472, 256, 0, stream>>>(x, out + (size_t)LL * BB * DD);
}